// Round 6
// baseline (843.821 us; speedup 1.0000x reference)
//
#include <hip/hip_runtime.h>
#include <math.h>

constexpr int N    = 100000;
constexpr int E    = 1600000;
constexpr int DIN  = 256;
constexpr int D    = 128;
constexpr int L    = 4;
constexpr float EPS = 1e-5f;
constexpr int NPP  = 12500;   // nodes per XCD partition (N/8)

typedef __attribute__((ext_vector_type(8))) short bf16x8;
typedef __attribute__((ext_vector_type(4))) float f32x4;

__device__ inline ushort f2b(float f) {
    uint u = __float_as_uint(f);
    uint r = u + 0x7fffu + ((u >> 16) & 1u);
    return (ushort)(r >> 16);
}
__device__ inline float b2f(ushort b) { return __uint_as_float(((uint)b) << 16); }

// async global->LDS, 16B per lane; lds must be the wave-uniform segment base
__device__ inline void gl_lds16(const void* g, void* lds) {
    __builtin_amdgcn_global_load_lds((const __attribute__((address_space(1))) void*)g,
                                     (__attribute__((address_space(3))) void*)lds,
                                     16, 0, 0);
}

// ---------------- CSR build ----------------

__global__ void k_count(const int* __restrict__ col, int* __restrict__ cnt) {
    int i = blockIdx.x * 256 + threadIdx.x;
    if (i * 2 + 1 < E) {
        int2 cc = ((const int2*)col)[i];
        atomicAdd(&cnt[cc.x], 1);
        atomicAdd(&cnt[cc.y], 1);
    } else if (i * 2 < E) {
        atomicAdd(&cnt[col[i * 2]], 1);
    }
}

__global__ void k_dis(const int* __restrict__ cnt, float* __restrict__ dis) {
    int n = blockIdx.x * 256 + threadIdx.x;
    if (n < N) dis[n] = rsqrtf((float)cnt[n] + 1.0f);   // +1 self-loop
}

__global__ void k_blocksum(const int* __restrict__ cnt, int* __restrict__ bsum) {
    __shared__ int s[256];
    int base = blockIdx.x * 1024;
    int t = threadIdx.x;
    int a = 0;
    for (int j = 0; j < 4; j++) {
        int idx = base + t * 4 + j;
        if (idx < N) a += cnt[idx];
    }
    s[t] = a; __syncthreads();
    for (int off = 128; off > 0; off >>= 1) {
        if (t < off) s[t] += s[t + off];
        __syncthreads();
    }
    if (t == 0) bsum[blockIdx.x] = s[0];
}

__global__ void k_scan(int* __restrict__ bsum, int nb) {
    __shared__ int s[128];
    int t = threadIdx.x;
    int v = (t < nb) ? bsum[t] : 0;
    s[t] = v; __syncthreads();
    for (int off = 1; off < 128; off <<= 1) {
        int x = (t >= off) ? s[t - off] : 0;
        __syncthreads();
        s[t] += x;
        __syncthreads();
    }
    if (t < nb) bsum[t] = s[t] - v;   // exclusive
}

__global__ void k_offsets(const int* __restrict__ cnt, const int* __restrict__ bsum,
                          int* __restrict__ offs) {
    __shared__ int ls[256];
    int b = blockIdx.x, t = threadIdx.x;
    int base = b * 1024;
    int v[4]; int s = 0;
    for (int j = 0; j < 4; j++) {
        int idx = base + t * 4 + j;
        v[j] = (idx < N) ? cnt[idx] : 0;
        s += v[j];
    }
    ls[t] = s; __syncthreads();
    for (int off = 1; off < 256; off <<= 1) {
        int x = (t >= off) ? ls[t - off] : 0;
        __syncthreads();
        ls[t] += x;
        __syncthreads();
    }
    int excl = ((t == 0) ? 0 : ls[t - 1]) + bsum[b];
    for (int j = 0; j < 4; j++) {
        int idx = base + t * 4 + j;
        if (idx < N) offs[idx] = excl;
        excl += v[j];
        if (idx == N - 1) offs[N] = excl;
    }
}

// XCD-partitioned scatter, 4 edges/thread (int4) for ILP
__global__ void k_scatter(const int* __restrict__ row, const int* __restrict__ col,
                          const float* __restrict__ dis, int* __restrict__ cur,
                          int2* __restrict__ csr) {
    int part = blockIdx.x & 7;
    int base = ((blockIdx.x >> 3) * 256 + threadIdx.x) * 4;
    if (base >= E) return;
    int4 c4 = *(const int4*)(col + base);
    int4 r4 = *(const int4*)(row + base);
    int cs[4] = {c4.x, c4.y, c4.z, c4.w};
    int rs[4] = {r4.x, r4.y, r4.z, r4.w};
    #pragma unroll
    for (int j = 0; j < 4; j++) {
        if (cs[j] / NPP == part) {
            int pos = atomicAdd(&cur[cs[j]], 1);
            csr[pos] = make_int2(rs[j], __float_as_int(dis[rs[j]] * dis[cs[j]]));
        }
    }
}

// ---------------- weight prep (bf16, identity folded) ----------------

__global__ void k_prep_w(const float* __restrict__ lin1_w, const float* __restrict__ w1,
                         const float* __restrict__ w2, float4 betas,
                         ushort* __restrict__ wb0, ushort* __restrict__ wbc) {
    int i = blockIdx.x * 256 + threadIdx.x;
    if (i < D * DIN) wb0[i] = f2b(lin1_w[i]);
    if (i < L * D * 256) {
        int l = i >> 15, r = i & 32767, d = r >> 8, k = r & 255;
        float beta = (l == 0) ? betas.x : (l == 1) ? betas.y : (l == 2) ? betas.z : betas.w;
        float v;
        if (k < 128) v = beta * w1[l * 16384 + k * 128 + d] + ((k == d) ? (1.f - beta) : 0.f);
        else { int kk = k - 128; v = beta * w2[l * 16384 + kk * 128 + d] + ((kk == d) ? (1.f - beta) : 0.f); }
        wbc[l * 32768 + d * 256 + k] = f2b(v);
    }
}

// ---------------- f0 GEMM: BM=64, BK=64 dbuf via global_load_lds ----------------
// LDS tile: row r (0..63) x 64 fp32 (256B, 16 chunks of 16B). chunk c stored at c^(r&7).
// global_load_lds writes linearly -> inverse swizzle applied to the SOURCE address.

__global__ __launch_bounds__(256, 4) void k_f0_mfma(const float* __restrict__ x,
        const ushort* __restrict__ wb, const float* __restrict__ bias,
        ushort* __restrict__ f_bf, ushort* __restrict__ x0_bf) {
    __shared__ float Ab[2][4096];   // 2 x 16 KB
    int t = threadIdx.x;
    int wv = t >> 6, lane = t & 63;
    int l16 = lane & 15, g16 = lane >> 4;
    int row0 = blockIdx.x * 64;

    f32x4 acc[8];
    #pragma unroll
    for (int n = 0; n < 8; n++) acc[n] = f32x4{0.f, 0.f, 0.f, 0.f};

    auto stage = [&](int bb, int tk) {
        #pragma unroll
        for (int it = 0; it < 4; it++) {
            int d = it * 256 + t;              // 16B chunk id (0..1023)
            int r = d >> 4, pc = d & 15;
            int lc = pc ^ (r & 7);             // inverse swizzle on source
            int gr = min(row0 + r, N - 1);
            const float* src = x + (size_t)gr * 256 + tk * 64 + lc * 4;
            char* ldsb = (char*)Ab[bb] + (it * 256 + wv * 64) * 16;  // wave-uniform
            gl_lds16(src, ldsb);
        }
    };

    auto compute = [&](int bb, int tk) {
        #pragma unroll
        for (int kk = 0; kk < 2; kk++) {
            int r = wv * 16 + l16;
            int c0 = kk * 8 + g16 * 2;
            float4 lo = *(const float4*)((char*)Ab[bb] + r * 256 + ((c0)     ^ (r & 7)) * 16);
            float4 hi = *(const float4*)((char*)Ab[bb] + r * 256 + ((c0 + 1) ^ (r & 7)) * 16);
            uint4 p;
            p.x = (uint)f2b(lo.x) | ((uint)f2b(lo.y) << 16);
            p.y = (uint)f2b(lo.z) | ((uint)f2b(lo.w) << 16);
            p.z = (uint)f2b(hi.x) | ((uint)f2b(hi.y) << 16);
            p.w = (uint)f2b(hi.z) | ((uint)f2b(hi.w) << 16);
            bf16x8 a = *(bf16x8*)&p;
            int ksg = tk * 2 + kk;
            #pragma unroll
            for (int n = 0; n < 8; n++) {
                bf16x8 b = *(const bf16x8*)(wb + (size_t)(n * 16 + l16) * 256 + ksg * 32 + g16 * 8);
                acc[n] = __builtin_amdgcn_mfma_f32_16x16x32_bf16(a, b, acc[n], 0, 0, 0);
            }
        }
    };

    stage(0, 0);
    __syncthreads();
    #pragma unroll
    for (int tk = 0; tk < 4; tk++) {
        if (tk < 3) stage((tk + 1) & 1, tk + 1);
        compute(tk & 1, tk);
        __syncthreads();
    }

    float bc[8];
    #pragma unroll
    for (int n = 0; n < 8; n++) bc[n] = bias[n * 16 + l16];
    #pragma unroll
    for (int j = 0; j < 4; j++) {
        int gr = row0 + wv * 16 + g16 * 4 + j;
        if (gr >= N) continue;
        #pragma unroll
        for (int n = 0; n < 8; n++) {
            float r = fmaxf(acc[n][j] + bc[n], 0.f);
            size_t o = (size_t)gr * 128 + n * 16 + l16;
            f_bf[o] = f2b(r);
            x0_bf[o] = f2b(0.5f * r);
        }
    }
}

// ---------------- combine GEMM: BM=64, A=[g|x0] 32KB single-stage ----------------
// LDS: row r (0..63) x 512B (32 chunks; 0-15 = g row, 16-31 = x0 row), chunk c at c^(r&7).

__global__ __launch_bounds__(256, 4) void k_combine_mfma(const ushort* __restrict__ g_bf,
        const ushort* __restrict__ x0_bf, const ushort* __restrict__ wb,
        ushort* __restrict__ h_bf, float* __restrict__ sr) {
    __shared__ ushort Ab[16384];   // 32 KB
    __shared__ float red1[256];
    __shared__ float red2[256];
    int t = threadIdx.x;
    int wv = t >> 6, lane = t & 63;
    int l16 = lane & 15, g16 = lane >> 4;
    int row0 = blockIdx.x * 64;

    #pragma unroll
    for (int it = 0; it < 8; it++) {
        int d = it * 256 + t;                  // chunk id (0..2047)
        int r = d >> 5, pc = d & 31;
        int lc = pc ^ (r & 7);                 // xor flips only low 3 bits: stays in g/x0 half
        int gr = min(row0 + r, N - 1);
        const ushort* src = (lc < 16) ? (g_bf + (size_t)gr * 128 + lc * 8)
                                      : (x0_bf + (size_t)gr * 128 + (lc - 16) * 8);
        char* ldsb = (char*)Ab + (it * 256 + wv * 64) * 16;   // wave-uniform
        gl_lds16(src, ldsb);
    }
    __syncthreads();

    f32x4 acc[8];
    #pragma unroll
    for (int n = 0; n < 8; n++) acc[n] = f32x4{0.f, 0.f, 0.f, 0.f};

    #pragma unroll
    for (int kk = 0; kk < 8; kk++) {
        int r = wv * 16 + l16;
        int c = kk * 4 + g16;
        bf16x8 a = *(const bf16x8*)((char*)Ab + r * 512 + (c ^ (r & 7)) * 16);
        #pragma unroll
        for (int n = 0; n < 8; n++) {
            bf16x8 b = *(const bf16x8*)(wb + (size_t)(n * 16 + l16) * 256 + kk * 32 + g16 * 8);
            acc[n] = __builtin_amdgcn_mfma_f32_16x16x32_bf16(a, b, acc[n], 0, 0, 0);
        }
    }

    // stats over valid rows only (stage clamps OOB rows to N-1 -> excluded here)
    float sum = 0.f, sq = 0.f;
    #pragma unroll
    for (int j = 0; j < 4; j++) {
        int gr = row0 + wv * 16 + g16 * 4 + j;
        if (gr < N) {
            #pragma unroll
            for (int n = 0; n < 8; n++) { float v = acc[n][j]; sum += v; sq += v * v; }
        }
    }

    #pragma unroll
    for (int j = 0; j < 4; j++) {
        int gr = row0 + wv * 16 + g16 * 4 + j;
        if (gr >= N) continue;
        #pragma unroll
        for (int n = 0; n < 8; n++)
            h_bf[(size_t)gr * 128 + n * 16 + l16] = f2b(acc[n][j]);
    }

    red1[t] = sum; red2[t] = sq; __syncthreads();
    for (int off = 128; off > 0; off >>= 1) {
        if (t < off) { red1[t] += red1[t + off]; red2[t] += red2[t + off]; }
        __syncthreads();
    }
    if (t == 0) { atomicAdd(&sr[0], red1[0]); atomicAdd(&sr[1], red2[0]); }
}

// ---------------- aggregation: wave/node, 16 lanes/row, 2-wide + prefetch, LN fused ----------------

template <int AFFINE>
__global__ __launch_bounds__(256) void k_agg(const ushort* __restrict__ src,
        const int* __restrict__ offs, const int2* __restrict__ csr,
        const float* __restrict__ dis, const float* __restrict__ sr,
        const float* __restrict__ nw, const float* __restrict__ nb,
        ushort* __restrict__ g_bf) {
    int node = blockIdx.x * 4 + (threadIdx.x >> 6);
    if (node >= N) return;
    int lane = threadIdx.x & 63;
    int q = lane >> 4, cl = lane & 15;       // lane owns channels [cl*8, cl*8+8)
    const uint4* fu = (const uint4*)src;     // row = 16 uint4

    float sc[8], sh[8];
    if constexpr (AFFINE) {
        const float inv_n = 1.0f / ((float)N * (float)D);
        float m = sr[0] * inv_n;
        float var = fmaxf(sr[1] * inv_n - m * m, 0.f);
        float inv = 1.0f / (sqrtf(var) + EPS);
        #pragma unroll
        for (int j = 0; j < 8; j++) {
            float w = nw[cl * 8 + j];
            sc[j] = inv * w;
            sh[j] = nb[cl * 8 + j] - m * inv * w;
        }
    }

    float a[8];
    #pragma unroll
    for (int j = 0; j < 8; j++) a[j] = 0.f;

    auto acc8 = [&](float val, uint4 rv) {
        uint vv[4] = {rv.x, rv.y, rv.z, rv.w};
        #pragma unroll
        for (int j2 = 0; j2 < 4; j2++) {
            float lo = b2f((ushort)(vv[j2] & 0xffffu));
            float hi = b2f((ushort)(vv[j2] >> 16));
            if constexpr (AFFINE) {
                lo = fmaxf(fmaf(lo, sc[2 * j2], sh[2 * j2]), 0.f);
                hi = fmaxf(fmaf(hi, sc[2 * j2 + 1], sh[2 * j2 + 1]), 0.f);
            }
            a[2 * j2]     += val * lo;
            a[2 * j2 + 1] += val * hi;
        }
    };

    float dv = dis[node];
    acc8((q == 0) ? dv * dv : 0.f, fu[(size_t)node * 16 + cl]);   // self loop

    int end = offs[node + 1];
    int i = offs[node] + q * 2;              // group q: edges q*2+{0,1} + j*8
    if (i < end) {
        int iA = i;
        int2 rA0 = csr[iA];
        int2 rA1 = csr[min(iA + 1, end - 1)];
        uint4 wA0 = fu[(size_t)rA0.x * 16 + cl];
        uint4 wA1 = fu[(size_t)rA1.x * 16 + cl];
        for (int iB = iA + 8; iB < end; iB += 8) {
            int2 rB0 = csr[iB];
            int2 rB1 = csr[min(iB + 1, end - 1)];
            uint4 wB0 = fu[(size_t)rB0.x * 16 + cl];
            uint4 wB1 = fu[(size_t)rB1.x * 16 + cl];
            acc8(__int_as_float(rA0.y), wA0);
            acc8(__int_as_float(rA1.y), wA1);
            iA = iB; rA0 = rB0; rA1 = rB1; wA0 = wB0; wA1 = wB1;
        }
        acc8(__int_as_float(rA0.y), wA0);
        if (iA + 1 < end) acc8(__int_as_float(rA1.y), wA1);
    }

    #pragma unroll
    for (int j = 0; j < 8; j++) {
        a[j] += __shfl_xor(a[j], 16, 64);
        a[j] += __shfl_xor(a[j], 32, 64);
    }
    if (q == 0) {
        uint4 o;
        o.x = (uint)f2b(0.5f * a[0]) | ((uint)f2b(0.5f * a[1]) << 16);
        o.y = (uint)f2b(0.5f * a[2]) | ((uint)f2b(0.5f * a[3]) << 16);
        o.z = (uint)f2b(0.5f * a[4]) | ((uint)f2b(0.5f * a[5]) << 16);
        o.w = (uint)f2b(0.5f * a[6]) | ((uint)f2b(0.5f * a[7]) << 16);
        ((uint4*)g_bf)[(size_t)node * 16 + cl] = o;
    }
}

// ---------------- final LN + relu -> fp32 out ----------------

__global__ void k_ln_final(const ushort* __restrict__ ob, const float* __restrict__ sr,
                           const float* __restrict__ nw, const float* __restrict__ nb,
                           float* __restrict__ fout) {
    int i = blockIdx.x * 256 + threadIdx.x;   // uint4 index: 8 bf16
    if (i >= N * 16) return;
    const float inv_n = 1.0f / ((float)N * (float)D);
    float m = sr[0] * inv_n;
    float var = fmaxf(sr[1] * inv_n - m * m, 0.f);
    float inv = 1.0f / (sqrtf(var) + EPS);
    uint4 v = ((const uint4*)ob)[i];
    int c = (i & 15) * 8;
    uint vv[4] = {v.x, v.y, v.z, v.w};
    float r[8];
    #pragma unroll
    for (int qd = 0; qd < 4; qd++) {
        float lo = b2f((ushort)(vv[qd] & 0xffff));
        float hi = b2f((ushort)(vv[qd] >> 16));
        r[2 * qd]     = fmaxf((lo - m) * inv * nw[c + 2 * qd]     + nb[c + 2 * qd], 0.f);
        r[2 * qd + 1] = fmaxf((hi - m) * inv * nw[c + 2 * qd + 1] + nb[c + 2 * qd + 1], 0.f);
    }
    float4 o0 = {r[0], r[1], r[2], r[3]};
    float4 o1 = {r[4], r[5], r[6], r[7]};
    ((float4*)fout)[2 * i] = o0;
    ((float4*)fout)[2 * i + 1] = o1;
}

// ---------------- launcher ----------------

extern "C" void kernel_launch(void* const* d_in, const int* in_sizes, int n_in,
                              void* d_out, int out_size, void* d_ws, size_t ws_size,
                              hipStream_t stream) {
    const float* x      = (const float*)d_in[0];
    const int*   ei     = (const int*)d_in[1];
    const float* lin1_w = (const float*)d_in[2];
    const float* lin1_b = (const float*)d_in[3];
    const float* w1     = (const float*)d_in[4];
    const float* w2     = (const float*)d_in[5];
    const float* nw     = (const float*)d_in[6];
    const float* nb     = (const float*)d_in[7];
    const int* row = ei;
    const int* col = ei + E;
    float* fout = (float*)d_out;

    char* ws = (char*)d_ws;
    size_t off0 = 0;
    auto alloc = [&](size_t bytes) -> char* {
        char* p = ws + off0;
        off0 = (off0 + bytes + 255) & ~(size_t)255;
        return p;
    };
    ushort* f_bf    = (ushort*)alloc((size_t)N * D * 2);   // f0 (post-relu)
    ushort* x0_bf   = (ushort*)alloc((size_t)N * D * 2);   // 0.5*f0
    ushort* g_bf    = (ushort*)alloc((size_t)N * D * 2);   // agg output
    ushort* h_bf    = (ushort*)alloc((size_t)N * D * 2);   // combine output (pre-LN)
    float*  dis     = (float*) alloc((size_t)N * 4);
    int*    cnt     = (int*)   alloc((size_t)N * 4);
    int*    offs    = (int*)   alloc((size_t)(N + 1) * 4);
    int*    cur     = (int*)   alloc((size_t)N * 4);
    int*    bsum    = (int*)   alloc((size_t)128 * 4);
    int2*   csr     = (int2*)  alloc((size_t)E * 8);
    float*  stats   = (float*) alloc(64);                  // 4 layers x {sum, sumsq}
    ushort* wb0     = (ushort*)alloc((size_t)D * DIN * 2);
    ushort* wbc     = (ushort*)alloc((size_t)L * D * 256 * 2);

    hipMemsetAsync(cnt, 0, (size_t)N * 4, stream);
    hipMemsetAsync(stats, 0, 64, stream);

    // CSR build
    k_count<<<(E / 2 + 255) / 256, 256, 0, stream>>>(col, cnt);
    k_dis<<<(N + 255) / 256, 256, 0, stream>>>(cnt, dis);
    int nbk = (N + 1023) / 1024;   // 98
    k_blocksum<<<nbk, 256, 0, stream>>>(cnt, bsum);
    k_scan<<<1, 128, 0, stream>>>(bsum, nbk);
    k_offsets<<<nbk, 256, 0, stream>>>(cnt, bsum, offs);
    hipMemcpyAsync(cur, offs, (size_t)N * 4, hipMemcpyDeviceToDevice, stream);
    int echunks = (E / 4 + 255) / 256;   // 1563
    k_scatter<<<echunks * 8, 256, 0, stream>>>(row, col, dis, cur, csr);

    // weight prep
    float4 betas;
    betas.x = logf(1.0f / 1.0f + 1.0f);
    betas.y = logf(1.0f / 2.0f + 1.0f);
    betas.z = logf(1.0f / 3.0f + 1.0f);
    betas.w = logf(1.0f / 4.0f + 1.0f);
    k_prep_w<<<(L * D * 256 + 255) / 256, 256, 0, stream>>>(lin1_w, w1, w2, betas, wb0, wbc);

    int GB = (N + 63) / 64;   // 1563
    k_f0_mfma<<<GB, 256, 0, stream>>>(x, wb0, lin1_b, f_bf, x0_bf);

    int AGB = (N + 3) / 4;
    for (int i = 0; i < L; i++) {
        if (i == 0)
            k_agg<0><<<AGB, 256, 0, stream>>>(f_bf, offs, csr, dis, nullptr, nw, nb, g_bf);
        else
            k_agg<1><<<AGB, 256, 0, stream>>>(h_bf, offs, csr, dis, stats + 2 * (i - 1), nw, nb, g_bf);
        k_combine_mfma<<<GB, 256, 0, stream>>>(g_bf, x0_bf, wbc + (size_t)i * D * 256,
                                               h_bf, stats + 2 * i);
    }
    k_ln_final<<<(N * 16 + 255) / 256, 256, 0, stream>>>(h_bf, stats + 6, nw, nb, fout);
}

// Round 8
// 573.705 us; speedup vs baseline: 1.4708x; 1.4708x over previous
//
#include <hip/hip_runtime.h>
#include <math.h>

constexpr int N    = 100000;
constexpr int E    = 1600000;
constexpr int DIN  = 256;
constexpr int D    = 128;
constexpr int L    = 4;
constexpr float EPS = 1e-5f;
constexpr int NPP  = 12500;   // nodes per XCD partition (N/8)

typedef __attribute__((ext_vector_type(8))) short bf16x8;
typedef __attribute__((ext_vector_type(4))) float f32x4;

__device__ inline ushort f2b(float f) {
    uint u = __float_as_uint(f);
    uint r = u + 0x7fffu + ((u >> 16) & 1u);
    return (ushort)(r >> 16);
}
__device__ inline float b2f(ushort b) { return __uint_as_float(((uint)b) << 16); }

// ---------------- CSR build ----------------

__global__ void k_count(const int* __restrict__ col, int* __restrict__ cnt) {
    int i = blockIdx.x * 256 + threadIdx.x;
    if (i * 2 + 1 < E) {
        int2 cc = ((const int2*)col)[i];
        atomicAdd(&cnt[cc.x], 1);
        atomicAdd(&cnt[cc.y], 1);
    } else if (i * 2 < E) {
        atomicAdd(&cnt[col[i * 2]], 1);
    }
}

__global__ void k_dis(const int* __restrict__ cnt, float* __restrict__ dis) {
    int n = blockIdx.x * 256 + threadIdx.x;
    if (n < N) dis[n] = rsqrtf((float)cnt[n] + 1.0f);   // +1 self-loop
}

__global__ void k_blocksum(const int* __restrict__ cnt, int* __restrict__ bsum) {
    __shared__ int s[256];
    int base = blockIdx.x * 1024;
    int t = threadIdx.x;
    int a = 0;
    for (int j = 0; j < 4; j++) {
        int idx = base + t * 4 + j;
        if (idx < N) a += cnt[idx];
    }
    s[t] = a; __syncthreads();
    for (int off = 128; off > 0; off >>= 1) {
        if (t < off) s[t] += s[t + off];
        __syncthreads();
    }
    if (t == 0) bsum[blockIdx.x] = s[0];
}

__global__ void k_scan(int* __restrict__ bsum, int nb) {
    __shared__ int s[128];
    int t = threadIdx.x;
    int v = (t < nb) ? bsum[t] : 0;
    s[t] = v; __syncthreads();
    for (int off = 1; off < 128; off <<= 1) {
        int x = (t >= off) ? s[t - off] : 0;
        __syncthreads();
        s[t] += x;
        __syncthreads();
    }
    if (t < nb) bsum[t] = s[t] - v;   // exclusive
}

__global__ void k_offsets(const int* __restrict__ cnt, const int* __restrict__ bsum,
                          int* __restrict__ offs) {
    __shared__ int ls[256];
    int b = blockIdx.x, t = threadIdx.x;
    int base = b * 1024;
    int v[4]; int s = 0;
    for (int j = 0; j < 4; j++) {
        int idx = base + t * 4 + j;
        v[j] = (idx < N) ? cnt[idx] : 0;
        s += v[j];
    }
    ls[t] = s; __syncthreads();
    for (int off = 1; off < 256; off <<= 1) {
        int x = (t >= off) ? ls[t - off] : 0;
        __syncthreads();
        ls[t] += x;
        __syncthreads();
    }
    int excl = ((t == 0) ? 0 : ls[t - 1]) + bsum[b];
    for (int j = 0; j < 4; j++) {
        int idx = base + t * 4 + j;
        if (idx < N) offs[idx] = excl;
        excl += v[j];
        if (idx == N - 1) offs[N] = excl;
    }
}

// XCD-partitioned scatter, 4 edges/thread (int4) for ILP
__global__ void k_scatter(const int* __restrict__ row, const int* __restrict__ col,
                          const float* __restrict__ dis, int* __restrict__ cur,
                          int2* __restrict__ csr) {
    int part = blockIdx.x & 7;
    int base = ((blockIdx.x >> 3) * 256 + threadIdx.x) * 4;
    if (base >= E) return;
    int4 c4 = *(const int4*)(col + base);
    int4 r4 = *(const int4*)(row + base);
    int cs[4] = {c4.x, c4.y, c4.z, c4.w};
    int rs[4] = {r4.x, r4.y, r4.z, r4.w};
    #pragma unroll
    for (int j = 0; j < 4; j++) {
        if (cs[j] / NPP == part) {
            int pos = atomicAdd(&cur[cs[j]], 1);
            csr[pos] = make_int2(rs[j], __float_as_int(dis[rs[j]] * dis[cs[j]]));
        }
    }
}

// ---------------- weight prep (bf16, identity folded) ----------------

__global__ void k_prep_w(const float* __restrict__ lin1_w, const float* __restrict__ w1,
                         const float* __restrict__ w2, float4 betas,
                         ushort* __restrict__ wb0, ushort* __restrict__ wbc) {
    int i = blockIdx.x * 256 + threadIdx.x;
    if (i < D * DIN) wb0[i] = f2b(lin1_w[i]);
    if (i < L * D * 256) {
        int l = i >> 15, r = i & 32767, d = r >> 8, k = r & 255;
        float beta = (l == 0) ? betas.x : (l == 1) ? betas.y : (l == 2) ? betas.z : betas.w;
        float v;
        if (k < 128) v = beta * w1[l * 16384 + k * 128 + d] + ((k == d) ? (1.f - beta) : 0.f);
        else { int kk = k - 128; v = beta * w2[l * 16384 + kk * 128 + d] + ((kk == d) ? (1.f - beta) : 0.f); }
        wbc[l * 32768 + d * 256 + k] = f2b(v);
    }
}

// ---------------- GEMM structure: B (64KB) in LDS once, waves independent ----------------
// B LDS layout: col c (0..127) x 32 chunks of 16B (k-range chunk ck = k/8).
// chunk ck of col c stored at uint4 index c*32 + (ck ^ (c&7)). XOR applied on BOTH
// write and read sides (same involution).

// f = relu(x @ lin1_w^T + b); f_bf <- bf16(f); x0_bf <- bf16(0.5f*f)
// 512 threads = 8 waves; each wave owns 16 rows; A preloaded to regs (16 uint4).
__global__ __launch_bounds__(512, 2) void k_f0_mfma(const float* __restrict__ x,
        const ushort* __restrict__ wb, const float* __restrict__ bias,
        ushort* __restrict__ f_bf, ushort* __restrict__ x0_bf) {
    __shared__ uint4 Bl[4096];   // 64 KB = 4096 uint4
    int t = threadIdx.x;
    #pragma unroll
    for (int it = 0; it < 8; it++) {            // 8 x 512 = 4096 chunks (FIX: was 4)
        int d = it * 512 + t, c = d >> 5, ck = d & 31;
        Bl[c * 32 + (ck ^ (c & 7))] = ((const uint4*)wb)[d];
    }
    __syncthreads();

    int wv = t >> 6, lane = t & 63;
    int l16 = lane & 15, g16 = lane >> 4;
    int row0 = (blockIdx.x * 8 + wv) * 16;
    if (row0 >= N) return;   // after barrier; full 16-row tiles (N % 16 == 0)

    // preload all A: 16 uint4 = row (row0+l16), k-quarter g16 within each ks
    const uint4* xb = (const uint4*)(x + (size_t)(row0 + l16) * 256);
    uint4 xr[16];
    #pragma unroll
    for (int ks = 0; ks < 8; ks++) {
        xr[2 * ks]     = xb[ks * 8 + g16 * 2];
        xr[2 * ks + 1] = xb[ks * 8 + g16 * 2 + 1];
    }

    f32x4 acc[8];
    #pragma unroll
    for (int n = 0; n < 8; n++) acc[n] = f32x4{0.f, 0.f, 0.f, 0.f};

    #pragma unroll
    for (int ks = 0; ks < 8; ks++) {
        float4 lo = *(const float4*)&xr[2 * ks];
        float4 hi = *(const float4*)&xr[2 * ks + 1];
        uint4 p;
        p.x = (uint)f2b(lo.x) | ((uint)f2b(lo.y) << 16);
        p.y = (uint)f2b(lo.z) | ((uint)f2b(lo.w) << 16);
        p.z = (uint)f2b(hi.x) | ((uint)f2b(hi.y) << 16);
        p.w = (uint)f2b(hi.z) | ((uint)f2b(hi.w) << 16);
        bf16x8 a = *(bf16x8*)&p;
        int xo = (ks * 4 + g16) ^ (l16 & 7);
        const char* bp = (const char*)Bl + l16 * 512 + xo * 16;
        #pragma unroll
        for (int n = 0; n < 8; n++) {
            bf16x8 b = *(const bf16x8*)(bp + n * 8192);
            acc[n] = __builtin_amdgcn_mfma_f32_16x16x32_bf16(a, b, acc[n], 0, 0, 0);
        }
    }

    float bc[8];
    #pragma unroll
    for (int n = 0; n < 8; n++) bc[n] = bias[n * 16 + l16];
    #pragma unroll
    for (int j = 0; j < 4; j++) {
        int gr = row0 + g16 * 4 + j;
        #pragma unroll
        for (int n = 0; n < 8; n++) {
            float r = fmaxf(acc[n][j] + bc[n], 0.f);
            size_t o = (size_t)gr * 128 + n * 16 + l16;
            f_bf[o] = f2b(r);
            x0_bf[o] = f2b(0.5f * r);
        }
    }
}

// out = [g|x0] @ wbc_l -> h_bf (pre-LN); LN stats -> atomicAdd(sr)
__global__ __launch_bounds__(512, 2) void k_combine_mfma(const ushort* __restrict__ g_bf,
        const ushort* __restrict__ x0_bf, const ushort* __restrict__ wb,
        ushort* __restrict__ h_bf, float* __restrict__ sr) {
    __shared__ uint4 Bl[4096];   // 64 KB
    __shared__ float red1[512];
    __shared__ float red2[512];
    int t = threadIdx.x;
    #pragma unroll
    for (int it = 0; it < 8; it++) {            // 8 x 512 = 4096 chunks (FIX: was 4)
        int d = it * 512 + t, c = d >> 5, ck = d & 31;
        Bl[c * 32 + (ck ^ (c & 7))] = ((const uint4*)wb)[d];
    }
    __syncthreads();

    int wv = t >> 6, lane = t & 63;
    int l16 = lane & 15, g16 = lane >> 4;
    int row0 = (blockIdx.x * 8 + wv) * 16;
    bool active = row0 < N;

    f32x4 acc[8];
    #pragma unroll
    for (int n = 0; n < 8; n++) acc[n] = f32x4{0.f, 0.f, 0.f, 0.f};

    if (active) {
        // preload all A: 8 uint4; ks 0-3 from g, 4-7 from x0
        const uint4* ga = (const uint4*)(g_bf  + (size_t)(row0 + l16) * 128);
        const uint4* xa = (const uint4*)(x0_bf + (size_t)(row0 + l16) * 128);
        uint4 ar[8];
        #pragma unroll
        for (int ks = 0; ks < 4; ks++) ar[ks]     = ga[ks * 4 + g16];
        #pragma unroll
        for (int ks = 0; ks < 4; ks++) ar[ks + 4] = xa[ks * 4 + g16];

        #pragma unroll
        for (int ks = 0; ks < 8; ks++) {
            bf16x8 a = *(bf16x8*)&ar[ks];
            int xo = (ks * 4 + g16) ^ (l16 & 7);
            const char* bp = (const char*)Bl + l16 * 512 + xo * 16;
            #pragma unroll
            for (int n = 0; n < 8; n++) {
                bf16x8 b = *(const bf16x8*)(bp + n * 8192);
                acc[n] = __builtin_amdgcn_mfma_f32_16x16x32_bf16(a, b, acc[n], 0, 0, 0);
            }
        }
    }

    float sum = 0.f, sq = 0.f;
    if (active) {
        #pragma unroll
        for (int n = 0; n < 8; n++)
            #pragma unroll
            for (int j = 0; j < 4; j++) { float v = acc[n][j]; sum += v; sq += v * v; }
        #pragma unroll
        for (int j = 0; j < 4; j++) {
            int gr = row0 + g16 * 4 + j;
            #pragma unroll
            for (int n = 0; n < 8; n++)
                h_bf[(size_t)gr * 128 + n * 16 + l16] = f2b(acc[n][j]);
        }
    }

    red1[t] = sum; red2[t] = sq; __syncthreads();
    for (int off = 256; off > 0; off >>= 1) {
        if (t < off) { red1[t] += red1[t + off]; red2[t] += red2[t + off]; }
        __syncthreads();
    }
    if (t == 0) { atomicAdd(&sr[0], red1[0]); atomicAdd(&sr[1], red2[0]); }
}

// ---------------- aggregation: wave/node, 16 lanes/row, 2-wide + prefetch, LN fused ----------------

template <int AFFINE>
__global__ __launch_bounds__(256) void k_agg(const ushort* __restrict__ src,
        const int* __restrict__ offs, const int2* __restrict__ csr,
        const float* __restrict__ dis, const float* __restrict__ sr,
        const float* __restrict__ nw, const float* __restrict__ nb,
        ushort* __restrict__ g_bf) {
    int node = blockIdx.x * 4 + (threadIdx.x >> 6);
    if (node >= N) return;
    int lane = threadIdx.x & 63;
    int q = lane >> 4, cl = lane & 15;       // lane owns channels [cl*8, cl*8+8)
    const uint4* fu = (const uint4*)src;     // row = 16 uint4

    float sc[8], sh[8];
    if constexpr (AFFINE) {
        const float inv_n = 1.0f / ((float)N * (float)D);
        float m = sr[0] * inv_n;
        float var = fmaxf(sr[1] * inv_n - m * m, 0.f);
        float inv = 1.0f / (sqrtf(var) + EPS);
        #pragma unroll
        for (int j = 0; j < 8; j++) {
            float w = nw[cl * 8 + j];
            sc[j] = inv * w;
            sh[j] = nb[cl * 8 + j] - m * inv * w;
        }
    }

    float a[8];
    #pragma unroll
    for (int j = 0; j < 8; j++) a[j] = 0.f;

    auto acc8 = [&](float val, uint4 rv) {
        uint vv[4] = {rv.x, rv.y, rv.z, rv.w};
        #pragma unroll
        for (int j2 = 0; j2 < 4; j2++) {
            float lo = b2f((ushort)(vv[j2] & 0xffffu));
            float hi = b2f((ushort)(vv[j2] >> 16));
            if constexpr (AFFINE) {
                lo = fmaxf(fmaf(lo, sc[2 * j2], sh[2 * j2]), 0.f);
                hi = fmaxf(fmaf(hi, sc[2 * j2 + 1], sh[2 * j2 + 1]), 0.f);
            }
            a[2 * j2]     += val * lo;
            a[2 * j2 + 1] += val * hi;
        }
    };

    float dv = dis[node];
    acc8((q == 0) ? dv * dv : 0.f, fu[(size_t)node * 16 + cl]);   // self loop

    int end = offs[node + 1];
    int i = offs[node] + q * 2;              // group q: edges q*2+{0,1} + j*8
    if (i < end) {
        int iA = i;
        int2 rA0 = csr[iA];
        int2 rA1 = csr[min(iA + 1, end - 1)];
        uint4 wA0 = fu[(size_t)rA0.x * 16 + cl];
        uint4 wA1 = fu[(size_t)rA1.x * 16 + cl];
        for (int iB = iA + 8; iB < end; iB += 8) {
            int2 rB0 = csr[iB];
            int2 rB1 = csr[min(iB + 1, end - 1)];
            uint4 wB0 = fu[(size_t)rB0.x * 16 + cl];
            uint4 wB1 = fu[(size_t)rB1.x * 16 + cl];
            acc8(__int_as_float(rA0.y), wA0);
            acc8(__int_as_float(rA1.y), wA1);
            iA = iB; rA0 = rB0; rA1 = rB1; wA0 = wB0; wA1 = wB1;
        }
        acc8(__int_as_float(rA0.y), wA0);
        if (iA + 1 < end) acc8(__int_as_float(rA1.y), wA1);
    }

    #pragma unroll
    for (int j = 0; j < 8; j++) {
        a[j] += __shfl_xor(a[j], 16, 64);
        a[j] += __shfl_xor(a[j], 32, 64);
    }
    if (q == 0) {
        uint4 o;
        o.x = (uint)f2b(0.5f * a[0]) | ((uint)f2b(0.5f * a[1]) << 16);
        o.y = (uint)f2b(0.5f * a[2]) | ((uint)f2b(0.5f * a[3]) << 16);
        o.z = (uint)f2b(0.5f * a[4]) | ((uint)f2b(0.5f * a[5]) << 16);
        o.w = (uint)f2b(0.5f * a[6]) | ((uint)f2b(0.5f * a[7]) << 16);
        ((uint4*)g_bf)[(size_t)node * 16 + cl] = o;
    }
}

// ---------------- final LN + relu -> fp32 out ----------------

__global__ void k_ln_final(const ushort* __restrict__ ob, const float* __restrict__ sr,
                           const float* __restrict__ nw, const float* __restrict__ nb,
                           float* __restrict__ fout) {
    int i = blockIdx.x * 256 + threadIdx.x;   // uint4 index: 8 bf16
    if (i >= N * 16) return;
    const float inv_n = 1.0f / ((float)N * (float)D);
    float m = sr[0] * inv_n;
    float var = fmaxf(sr[1] * inv_n - m * m, 0.f);
    float inv = 1.0f / (sqrtf(var) + EPS);
    uint4 v = ((const uint4*)ob)[i];
    int c = (i & 15) * 8;
    uint vv[4] = {v.x, v.y, v.z, v.w};
    float r[8];
    #pragma unroll
    for (int qd = 0; qd < 4; qd++) {
        float lo = b2f((ushort)(vv[qd] & 0xffff));
        float hi = b2f((ushort)(vv[qd] >> 16));
        r[2 * qd]     = fmaxf((lo - m) * inv * nw[c + 2 * qd]     + nb[c + 2 * qd], 0.f);
        r[2 * qd + 1] = fmaxf((hi - m) * inv * nw[c + 2 * qd + 1] + nb[c + 2 * qd + 1], 0.f);
    }
    float4 o0 = {r[0], r[1], r[2], r[3]};
    float4 o1 = {r[4], r[5], r[6], r[7]};
    ((float4*)fout)[2 * i] = o0;
    ((float4*)fout)[2 * i + 1] = o1;
}

// ---------------- launcher ----------------

extern "C" void kernel_launch(void* const* d_in, const int* in_sizes, int n_in,
                              void* d_out, int out_size, void* d_ws, size_t ws_size,
                              hipStream_t stream) {
    const float* x      = (const float*)d_in[0];
    const int*   ei     = (const int*)d_in[1];
    const float* lin1_w = (const float*)d_in[2];
    const float* lin1_b = (const float*)d_in[3];
    const float* w1     = (const float*)d_in[4];
    const float* w2     = (const float*)d_in[5];
    const float* nw     = (const float*)d_in[6];
    const float* nb     = (const float*)d_in[7];
    const int* row = ei;
    const int* col = ei + E;
    float* fout = (float*)d_out;

    char* ws = (char*)d_ws;
    size_t off0 = 0;
    auto alloc = [&](size_t bytes) -> char* {
        char* p = ws + off0;
        off0 = (off0 + bytes + 255) & ~(size_t)255;
        return p;
    };
    ushort* f_bf    = (ushort*)alloc((size_t)N * D * 2);   // f0 (post-relu)
    ushort* x0_bf   = (ushort*)alloc((size_t)N * D * 2);   // 0.5*f0
    ushort* g_bf    = (ushort*)alloc((size_t)N * D * 2);   // agg output
    ushort* h_bf    = (ushort*)alloc((size_t)N * D * 2);   // combine output (pre-LN)
    float*  dis     = (float*) alloc((size_t)N * 4);
    int*    cnt     = (int*)   alloc((size_t)N * 4);
    int*    offs    = (int*)   alloc((size_t)(N + 1) * 4);
    int*    cur     = (int*)   alloc((size_t)N * 4);
    int*    bsum    = (int*)   alloc((size_t)128 * 4);
    int2*   csr     = (int2*)  alloc((size_t)E * 8);
    float*  stats   = (float*) alloc(64);                  // 4 layers x {sum, sumsq}
    ushort* wb0     = (ushort*)alloc((size_t)D * DIN * 2);
    ushort* wbc     = (ushort*)alloc((size_t)L * D * 256 * 2);

    hipMemsetAsync(cnt, 0, (size_t)N * 4, stream);
    hipMemsetAsync(stats, 0, 64, stream);

    // CSR build
    k_count<<<(E / 2 + 255) / 256, 256, 0, stream>>>(col, cnt);
    k_dis<<<(N + 255) / 256, 256, 0, stream>>>(cnt, dis);
    int nbk = (N + 1023) / 1024;   // 98
    k_blocksum<<<nbk, 256, 0, stream>>>(cnt, bsum);
    k_scan<<<1, 128, 0, stream>>>(bsum, nbk);
    k_offsets<<<nbk, 256, 0, stream>>>(cnt, bsum, offs);
    hipMemcpyAsync(cur, offs, (size_t)N * 4, hipMemcpyDeviceToDevice, stream);
    int echunks = (E / 4 + 255) / 256;   // 1563
    k_scatter<<<echunks * 8, 256, 0, stream>>>(row, col, dis, cur, csr);

    // weight prep
    float4 betas;
    betas.x = logf(1.0f / 1.0f + 1.0f);
    betas.y = logf(1.0f / 2.0f + 1.0f);
    betas.z = logf(1.0f / 3.0f + 1.0f);
    betas.w = logf(1.0f / 4.0f + 1.0f);
    k_prep_w<<<(L * D * 256 + 255) / 256, 256, 0, stream>>>(lin1_w, w1, w2, betas, wb0, wbc);

    int GB = (N / 16 + 7) / 8;   // 782 blocks x 8 waves x 16 rows
    k_f0_mfma<<<GB, 512, 0, stream>>>(x, wb0, lin1_b, f_bf, x0_bf);

    int AGB = (N + 3) / 4;
    for (int i = 0; i < L; i++) {
        if (i == 0)
            k_agg<0><<<AGB, 256, 0, stream>>>(f_bf, offs, csr, dis, nullptr, nw, nb, g_bf);
        else
            k_agg<1><<<AGB, 256, 0, stream>>>(h_bf, offs, csr, dis, stats + 2 * (i - 1), nw, nb, g_bf);
        k_combine_mfma<<<GB, 512, 0, stream>>>(g_bf, x0_bf, wbc + (size_t)i * D * 256,
                                               h_bf, stats + 2 * i);
    }
    k_ln_final<<<(N * 16 + 255) / 256, 256, 0, stream>>>(h_bf, stats + 6, nw, nb, fout);
}